// Round 13
// baseline (47.978 us; speedup 1.0000x reference)
//
#include <hip/hip_runtime.h>
#include <math.h>

#define RR 32
#define R3 (RR*RR*RR)
#define BATCH 8
#define NPTS 32768
#define CCH 64

typedef float vfloat4 __attribute__((ext_vector_type(4)));

static constexpr int SB   = 64;               // stats slots per batch
static constexpr int SBT  = SB * BATCH;       // 512 stats blocks
static constexpr int VZB  = 1024;             // voxf zero blocks (64KB each)
static constexpr int CZB  = 16;               // counts zero blocks
static constexpr int WPB  = 128;              // feat waves per batch
static constexpr int PPW  = NPTS / WPB;       // 256 points per wave
static constexpr int CHUNK = 64;              // points per chunk
static constexpr int NCH  = PPW / CHUNK;      // 4 chunks per wave
static constexpr int FGRID = (WPB / 4) * BATCH;  // 256 feat blocks total

// ws layout
static constexpr size_t OFF_COUNTS   = 0;                         // B*R3 ints = 1 MiB
static constexpr size_t OFF_PARTIALS = 1u << 20;                  // SBT*3 floats
static constexpr size_t OFF_CTRL     = (1u << 20) + (64u << 10);  // [done, listlen]
static constexpr size_t OFF_LIST     = (1u << 20) + (128u << 10); // hot list, 1 MiB max

// ---------------- K1: slotted stats partials + zero voxf + zero counts/ctrl ----------------
__global__ __launch_bounds__(256) void prep_kernel(const float* __restrict__ coords,
                                                   float* __restrict__ voxf,
                                                   int* __restrict__ counts,
                                                   float* __restrict__ partials,
                                                   int* __restrict__ ctrl) {
    int bx = blockIdx.x;
    int tid = threadIdx.x;
    if (bx < SBT) {
        int b = bx >> 6, sb = bx & 63;
        const float* cbase = coords + ((size_t)b * NPTS + sb * (NPTS / SB)) * 3;
        float sx = 0.f, sy = 0.f, sz = 0.f;
        #pragma unroll
        for (int k = 0; k < (NPTS / SB) / 256; ++k) {
            const float* p = cbase + (k * 256 + tid) * 3;
            float x = p[0], y = p[1], z = p[2];
            float m = (x + y + z) * (1.0f / 3.0f);
            float dx = x - m, dy = y - m, dz = z - m;
            sx += dx * dx; sy += dy * dy; sz += dz * dz;
        }
        #pragma unroll
        for (int off = 1; off < 64; off <<= 1) {
            sx += __shfl_xor(sx, off);
            sy += __shfl_xor(sy, off);
            sz += __shfl_xor(sz, off);
        }
        __shared__ float ls[3][4];
        int w = tid >> 6;
        if ((tid & 63) == 0) { ls[0][w] = sx; ls[1][w] = sy; ls[2][w] = sz; }
        __syncthreads();
        if (tid == 0) {
            float* o = partials + (size_t)bx * 3;
            o[0] = ls[0][0] + ls[0][1] + ls[0][2] + ls[0][3];
            o[1] = ls[1][0] + ls[1][1] + ls[1][2] + ls[1][3];
            o[2] = ls[2][0] + ls[2][1] + ls[2][2] + ls[2][3];
        }
        return;
    }
    int zb = bx - SBT;
    vfloat4 z = (vfloat4)(0.f);
    if (zb < VZB) {
        vfloat4* o4 = (vfloat4*)voxf + (size_t)zb * 4096;   // 64KB slice
        #pragma unroll
        for (int k = 0; k < 16; ++k) o4[k * 256 + tid] = z;
    } else {
        if (zb == VZB && tid < 2) ctrl[tid] = 0;            // done, listlen
        vfloat4* c4 = (vfloat4*)counts + (size_t)(zb - VZB) * 4096;
        #pragma unroll
        for (int k = 0; k < 16; ++k) c4[k * 256 + tid] = z;
    }
}

// ---------------- K2: fused points+feat + last-block inline scale ----------------
// Per wave: 4 chunks of 64 points, double-buffered 16xfloat4 tiles, run-length
// merged flushes (unscaled). First toucher of each voxel (count atomicAdd
// returning 0) appends (b,v) to the hot list. The last block to finish
// rescales the listed voxels by 1/count -- no separate scale kernel/boundary.
__global__ __launch_bounds__(256) void feat_kernel(const float* __restrict__ features,
                                                   const float* __restrict__ coords,
                                                   const float* __restrict__ partials,
                                                   float* __restrict__ nc_out,
                                                   int* __restrict__ counts,
                                                   float* __restrict__ voxf,
                                                   int* __restrict__ ctrl,
                                                   int* __restrict__ list) {
    int b = blockIdx.y;
    int tid = threadIdx.x;
    int w = blockIdx.x * 4 + (tid >> 6);       // wave within batch 0..WPB-1
    int lane = tid & 63;
    int sub = lane >> 4;
    int cb  = (lane & 15) << 2;
    const float* fbase = features + (size_t)b * NPTS * CCH;
    const float* crd = coords + (size_t)b * NPTS * 3;
    int* cnt = counts + (size_t)b * R3;
    float* obase = voxf + (size_t)b * CCH * R3;
    int p0 = w * PPW;

    // issue chunk-0 feature tile immediately
    float4 fbuf[2][16];
    #pragma unroll
    for (int i = 0; i < 16; ++i)
        fbuf[0][i] = *(const float4*)(fbase + (size_t)(p0 + i * 4 + sub) * CCH + cb);

    // per-wave denom re-reduce from slotted partials (lane = slot)
    const float* ps = partials + ((size_t)b * SB + lane) * 3;
    float qx = ps[0], qy = ps[1], qz = ps[2];
    #pragma unroll
    for (int off = 1; off < 64; off <<= 1) {
        qx += __shfl_xor(qx, off);
        qy += __shfl_xor(qy, off);
        qz += __shfl_xor(qz, off);
    }
    float mx = fmaxf(fmaxf(sqrtf(qx), sqrtf(qy)), sqrtf(qz));
    float rd = 0.5f / mx;                      // 1/denom, denom = 2*mx

    float4 acc = make_float4(0.f, 0.f, 0.f, 0.f);
    int curv = -1;
    int nrun = 0;

    auto flushRun = [&]() {
        if (curv < 0) return;
        if (lane == 0) {
            int old = atomicAdd(&cnt[curv], nrun);
            if (old == 0) {
                int p = atomicAdd(&ctrl[1], 1);
                __hip_atomic_store(&list[p], (b << 15) | curv,
                                   __ATOMIC_RELAXED, __HIP_MEMORY_SCOPE_AGENT);
            }
        }
        float sx = acc.x, sy = acc.y, sz = acc.z, sw = acc.w;
        sx += __shfl_xor(sx, 16); sx += __shfl_xor(sx, 32);
        sy += __shfl_xor(sy, 16); sy += __shfl_xor(sy, 32);
        sz += __shfl_xor(sz, 16); sz += __shfl_xor(sz, 32);
        sw += __shfl_xor(sw, 16); sw += __shfl_xor(sw, 32);
        float val = (sub == 0) ? sx : (sub == 1) ? sy : (sub == 2) ? sz : sw;
        atomicAdd(&obase[(size_t)(cb + sub) * R3 + curv], val);
    };

    #pragma unroll
    for (int c = 0; c < NCH; ++c) {
        int cur = c & 1;
        if (c + 1 < NCH) {
            #pragma unroll
            for (int i = 0; i < 16; ++i)
                fbuf[cur ^ 1][i] = *(const float4*)(fbase +
                    (size_t)(p0 + (c + 1) * CHUNK + i * 4 + sub) * CCH + cb);
        }
        int pp = p0 + c * CHUNK + lane;
        float x = crd[pp * 3], y = crd[pp * 3 + 1], zz = crd[pp * 3 + 2];
        float m = (x + y + zz) * (1.0f / 3.0f);
        float fx = (x - m) * rd + 0.5f;
        float fy = (y - m) * rd + 0.5f;
        float fz = (zz - m) * rd + 0.5f;
        float tx = fminf(fmaxf(fx * (float)RR, 0.0f), (float)(RR - 1));
        float ty = fminf(fmaxf(fy * (float)RR, 0.0f), (float)(RR - 1));
        float tz = fminf(fmaxf(fz * (float)RR, 0.0f), (float)(RR - 1));
        float* onc = nc_out + (size_t)(b * NPTS + pp) * 3;
        onc[0] = tx; onc[1] = ty; onc[2] = tz;
        int v = (int)rintf(tx) * (RR * RR) + (int)rintf(ty) * RR + (int)rintf(tz);

        int v0 = __shfl(v, 0);
        if (__all(v == v0)) {
            if (v0 != curv) {
                flushRun();
                acc = make_float4(0.f, 0.f, 0.f, 0.f);
                nrun = 0;
                curv = v0;
            }
            #pragma unroll
            for (int i = 0; i < 16; ++i) {
                acc.x += fbuf[cur][i].x; acc.y += fbuf[cur][i].y;
                acc.z += fbuf[cur][i].z; acc.w += fbuf[cur][i].w;
            }
            nrun += CHUNK;
        } else {
            // rare: mixed voxels within chunk -> per-point atomics
            flushRun();
            acc = make_float4(0.f, 0.f, 0.f, 0.f);
            nrun = 0;
            curv = -1;
            int old = atomicAdd(&cnt[v], 1);
            if (old == 0) {
                int p = atomicAdd(&ctrl[1], 1);
                __hip_atomic_store(&list[p], (b << 15) | v,
                                   __ATOMIC_RELAXED, __HIP_MEMORY_SCOPE_AGENT);
            }
            #pragma unroll
            for (int i = 0; i < 16; ++i) {
                int vv = __shfl(v, i * 4 + sub);
                size_t o = (size_t)cb * R3 + vv;
                atomicAdd(&obase[o],          fbuf[cur][i].x);
                atomicAdd(&obase[o + R3],     fbuf[cur][i].y);
                atomicAdd(&obase[o + 2 * R3], fbuf[cur][i].z);
                atomicAdd(&obase[o + 3 * R3], fbuf[cur][i].w);
            }
        }
    }
    flushRun();

    // -------- last-block inline scale (rocPRIM-style completion pattern) --------
    __threadfence();                           // release this block's atomics
    __shared__ int sh_last;
    __syncthreads();
    if (tid == 0) sh_last = (atomicAdd(&ctrl[0], 1) == FGRID - 1);
    __syncthreads();
    if (!sh_last) return;
    __threadfence();                           // acquire all blocks' atomics
    int n = __hip_atomic_load(&ctrl[1], __ATOMIC_RELAXED, __HIP_MEMORY_SCOPE_AGENT);
    int wv = tid >> 6;
    for (int e = wv; e < n; e += 4) {
        int packed = __hip_atomic_load(&list[e], __ATOMIC_RELAXED, __HIP_MEMORY_SCOPE_AGENT);
        int bb = packed >> 15;
        int v  = packed & (R3 - 1);
        int c  = __hip_atomic_load(&counts[(size_t)bb * R3 + v],
                                   __ATOMIC_RELAXED, __HIP_MEMORY_SCOPE_AGENT);
        if (c > 1) {
            float s = 1.0f / (float)c;
            size_t o = ((size_t)(bb * CCH) + lane) * R3 + v;
            float curf = __hip_atomic_load(&voxf[o], __ATOMIC_RELAXED, __HIP_MEMORY_SCOPE_AGENT);
            __hip_atomic_store(&voxf[o], curf * s, __ATOMIC_RELAXED, __HIP_MEMORY_SCOPE_AGENT);
        }
    }
}

extern "C" void kernel_launch(void* const* d_in, const int* in_sizes, int n_in,
                              void* d_out, int out_size, void* d_ws, size_t ws_size,
                              hipStream_t stream) {
    const float* features = (const float*)d_in[0];
    const float* coords   = (const float*)d_in[1];
    float* out = (float*)d_out;

    float* voxf = out;                                    // (B, C, R, R, R)
    float* nc   = out + (size_t)BATCH * CCH * R3;         // (B, N, 3)

    char* ws = (char*)d_ws;
    int*   counts   = (int*)(ws + OFF_COUNTS);
    float* partials = (float*)(ws + OFF_PARTIALS);
    int*   ctrl     = (int*)(ws + OFF_CTRL);
    int*   list     = (int*)(ws + OFF_LIST);

    prep_kernel<<<SBT + VZB + CZB, 256, 0, stream>>>(coords, voxf, counts, partials, ctrl);

    dim3 fgrid(WPB / 4, BATCH);                           // 32 x 8 = 256 blocks
    feat_kernel<<<fgrid, 256, 0, stream>>>(features, coords, partials, nc, counts,
                                           voxf, ctrl, list);
}

// Round 14
// 34.691 us; speedup vs baseline: 1.3830x; 1.3830x over previous
//
#include <hip/hip_runtime.h>
#include <math.h>

#define RR 32
#define R3 (RR*RR*RR)
#define BATCH 8
#define NPTS 32768
#define CCH 64

typedef float vfloat4 __attribute__((ext_vector_type(4)));

static constexpr int SB   = 64;               // stats slots per batch
static constexpr int SBT  = SB * BATCH;       // 512 stats blocks
static constexpr int VZB  = 1024;             // voxf zero blocks (64KB each)
static constexpr int CZB  = 16;               // counts zero blocks
static constexpr int WPB  = 256;              // feat waves per batch (2 blocks/CU)
static constexpr int PPW  = NPTS / WPB;       // 128 points per wave
static constexpr int CHUNK = 64;              // points per chunk
static constexpr int NCH  = PPW / CHUNK;      // 2 chunks per wave

// ws layout
static constexpr size_t OFF_COUNTS   = 0;                 // B*R3 ints = 1 MiB
static constexpr size_t OFF_PARTIALS = 1u << 20;          // SBT*3 floats

// ---------------- K1: slotted stats partials + zero voxf + zero counts ----------------
__global__ __launch_bounds__(256) void prep_kernel(const float* __restrict__ coords,
                                                   float* __restrict__ voxf,
                                                   int* __restrict__ counts,
                                                   float* __restrict__ partials) {
    int bx = blockIdx.x;
    int tid = threadIdx.x;
    if (bx < SBT) {
        int b = bx >> 6, sb = bx & 63;
        const float* cbase = coords + ((size_t)b * NPTS + sb * (NPTS / SB)) * 3;
        float sx = 0.f, sy = 0.f, sz = 0.f;
        #pragma unroll
        for (int k = 0; k < (NPTS / SB) / 256; ++k) {
            const float* p = cbase + (k * 256 + tid) * 3;
            float x = p[0], y = p[1], z = p[2];
            float m = (x + y + z) * (1.0f / 3.0f);
            float dx = x - m, dy = y - m, dz = z - m;
            sx += dx * dx; sy += dy * dy; sz += dz * dz;
        }
        #pragma unroll
        for (int off = 1; off < 64; off <<= 1) {
            sx += __shfl_xor(sx, off);
            sy += __shfl_xor(sy, off);
            sz += __shfl_xor(sz, off);
        }
        __shared__ float ls[3][4];
        int w = tid >> 6;
        if ((tid & 63) == 0) { ls[0][w] = sx; ls[1][w] = sy; ls[2][w] = sz; }
        __syncthreads();
        if (tid == 0) {
            float* o = partials + (size_t)bx * 3;
            o[0] = ls[0][0] + ls[0][1] + ls[0][2] + ls[0][3];
            o[1] = ls[1][0] + ls[1][1] + ls[1][2] + ls[1][3];
            o[2] = ls[2][0] + ls[2][1] + ls[2][2] + ls[2][3];
        }
        return;
    }
    int zb = bx - SBT;
    vfloat4 z = (vfloat4)(0.f);
    if (zb < VZB) {
        vfloat4* o4 = (vfloat4*)voxf + (size_t)zb * 4096;   // 64KB slice
        #pragma unroll
        for (int k = 0; k < 16; ++k) o4[k * 256 + tid] = z;
    } else {
        vfloat4* c4 = (vfloat4*)counts + (size_t)(zb - VZB) * 4096;
        #pragma unroll
        for (int k = 0; k < 16; ++k) c4[k * 256 + tid] = z;
    }
}

// ---------------- K2: fused points+feat, 128 points/wave, run-length flush ----------------
// Per wave: 2 chunks of 64 points, double-buffered 16xfloat4 tile loads.
// lane=(sub,cslice). Run-length merge across chunks; flush = one atomic per
// lane (channel cb+sub) after a 2-level shfl reduce + transpose.
__global__ __launch_bounds__(256) void feat_kernel(const float* __restrict__ features,
                                                   const float* __restrict__ coords,
                                                   const float* __restrict__ partials,
                                                   float* __restrict__ nc_out,
                                                   int* __restrict__ counts,
                                                   float* __restrict__ voxf) {
    int b = blockIdx.y;
    int tid = threadIdx.x;
    int w = blockIdx.x * 4 + (tid >> 6);       // wave within batch 0..WPB-1
    int lane = tid & 63;
    int sub = lane >> 4;
    int cb  = (lane & 15) << 2;
    const float* fbase = features + (size_t)b * NPTS * CCH;
    const float* crd = coords + (size_t)b * NPTS * 3;
    int* cnt = counts + (size_t)b * R3;
    float* obase = voxf + (size_t)b * CCH * R3;
    int p0 = w * PPW;

    // issue chunk-0 feature tile immediately
    float4 fbuf[2][16];
    #pragma unroll
    for (int i = 0; i < 16; ++i)
        fbuf[0][i] = *(const float4*)(fbase + (size_t)(p0 + i * 4 + sub) * CCH + cb);

    // per-wave denom re-reduce from slotted partials (lane = slot)
    const float* ps = partials + ((size_t)b * SB + lane) * 3;
    float qx = ps[0], qy = ps[1], qz = ps[2];
    #pragma unroll
    for (int off = 1; off < 64; off <<= 1) {
        qx += __shfl_xor(qx, off);
        qy += __shfl_xor(qy, off);
        qz += __shfl_xor(qz, off);
    }
    float mx = fmaxf(fmaxf(sqrtf(qx), sqrtf(qy)), sqrtf(qz));
    float rd = 0.5f / mx;                      // 1/denom, denom = 2*mx

    float4 acc = make_float4(0.f, 0.f, 0.f, 0.f);
    int curv = -1;
    int nrun = 0;

    auto flushRun = [&]() {
        if (curv < 0) return;
        if (lane == 0) atomicAdd(&cnt[curv], nrun);
        float sx = acc.x, sy = acc.y, sz = acc.z, sw = acc.w;
        sx += __shfl_xor(sx, 16); sx += __shfl_xor(sx, 32);
        sy += __shfl_xor(sy, 16); sy += __shfl_xor(sy, 32);
        sz += __shfl_xor(sz, 16); sz += __shfl_xor(sz, 32);
        sw += __shfl_xor(sw, 16); sw += __shfl_xor(sw, 32);
        float val = (sub == 0) ? sx : (sub == 1) ? sy : (sub == 2) ? sz : sw;
        atomicAdd(&obase[(size_t)(cb + sub) * R3 + curv], val);
    };

    #pragma unroll
    for (int c = 0; c < NCH; ++c) {
        int cur = c & 1;
        // prefetch next chunk's tile (in flight during this chunk's processing)
        if (c + 1 < NCH) {
            #pragma unroll
            for (int i = 0; i < 16; ++i)
                fbuf[cur ^ 1][i] = *(const float4*)(fbase +
                    (size_t)(p0 + (c + 1) * CHUNK + i * 4 + sub) * CCH + cb);
        }
        // this lane's own point for chunk c: nc + voxel id
        int pp = p0 + c * CHUNK + lane;
        float x = crd[pp * 3], y = crd[pp * 3 + 1], zz = crd[pp * 3 + 2];
        float m = (x + y + zz) * (1.0f / 3.0f);
        float fx = (x - m) * rd + 0.5f;
        float fy = (y - m) * rd + 0.5f;
        float fz = (zz - m) * rd + 0.5f;
        float tx = fminf(fmaxf(fx * (float)RR, 0.0f), (float)(RR - 1));
        float ty = fminf(fmaxf(fy * (float)RR, 0.0f), (float)(RR - 1));
        float tz = fminf(fmaxf(fz * (float)RR, 0.0f), (float)(RR - 1));
        float* onc = nc_out + (size_t)(b * NPTS + pp) * 3;
        onc[0] = tx; onc[1] = ty; onc[2] = tz;
        int v = (int)rintf(tx) * (RR * RR) + (int)rintf(ty) * RR + (int)rintf(tz);

        int v0 = __shfl(v, 0);
        if (__all(v == v0)) {
            if (v0 != curv) {
                flushRun();
                acc = make_float4(0.f, 0.f, 0.f, 0.f);
                nrun = 0;
                curv = v0;
            }
            #pragma unroll
            for (int i = 0; i < 16; ++i) {
                acc.x += fbuf[cur][i].x; acc.y += fbuf[cur][i].y;
                acc.z += fbuf[cur][i].z; acc.w += fbuf[cur][i].w;
            }
            nrun += CHUNK;
        } else {
            // rare: mixed voxels within chunk -> per-point atomics
            flushRun();
            acc = make_float4(0.f, 0.f, 0.f, 0.f);
            nrun = 0;
            curv = -1;
            atomicAdd(&cnt[v], 1);
            #pragma unroll
            for (int i = 0; i < 16; ++i) {
                int vv = __shfl(v, i * 4 + sub);
                size_t o = (size_t)cb * R3 + vv;
                atomicAdd(&obase[o],          fbuf[cur][i].x);
                atomicAdd(&obase[o + R3],     fbuf[cur][i].y);
                atomicAdd(&obase[o + 2 * R3], fbuf[cur][i].z);
                atomicAdd(&obase[o + 3 * R3], fbuf[cur][i].w);
            }
        }
    }
    flushRun();
}

// ---------------- K3: divide hot voxels by their counts ----------------
__global__ __launch_bounds__(256) void scale_kernel(const int* __restrict__ counts,
                                                    float* __restrict__ out) {
    int t = blockIdx.x * 256 + threadIdx.x;        // 0 .. B*R3-1
    int lane = threadIdx.x & 63;
    int b = t >> 15;                               // R3 = 32768
    int vox = t & (R3 - 1);
    int cnt = counts[t];
    unsigned long long mask = __ballot(cnt > 1);
    while (mask) {
        int src = __ffsll((long long)mask) - 1;
        mask &= mask - 1;
        int vv = __shfl(vox, src);
        int bb = __shfl(b, src);
        int cc = __shfl(cnt, src);
        float s = 1.0f / (float)cc;
        size_t o = ((size_t)bb * CCH + lane) * R3 + vv;
        out[o] *= s;
    }
}

extern "C" void kernel_launch(void* const* d_in, const int* in_sizes, int n_in,
                              void* d_out, int out_size, void* d_ws, size_t ws_size,
                              hipStream_t stream) {
    const float* features = (const float*)d_in[0];
    const float* coords   = (const float*)d_in[1];
    float* out = (float*)d_out;

    float* voxf = out;                                    // (B, C, R, R, R)
    float* nc   = out + (size_t)BATCH * CCH * R3;         // (B, N, 3)

    char* ws = (char*)d_ws;
    int*   counts   = (int*)(ws + OFF_COUNTS);
    float* partials = (float*)(ws + OFF_PARTIALS);

    prep_kernel<<<SBT + VZB + CZB, 256, 0, stream>>>(coords, voxf, counts, partials);

    dim3 fgrid(WPB / 4, BATCH);                           // 64 x 8 = 512 blocks
    feat_kernel<<<fgrid, 256, 0, stream>>>(features, coords, partials, nc, counts, voxf);

    scale_kernel<<<BATCH * R3 / 256, 256, 0, stream>>>(counts, voxf);
}

// Round 15
// 30.692 us; speedup vs baseline: 1.5632x; 1.1303x over previous
//
#include <hip/hip_runtime.h>
#include <math.h>

#define RR 32
#define R3 (RR*RR*RR)
#define BATCH 8
#define NPTS 32768
#define CCH 64

typedef float vfloat4 __attribute__((ext_vector_type(4)));

static constexpr int SB   = 64;               // stats slots per batch
static constexpr int SBT  = SB * BATCH;       // 512 stats blocks
static constexpr int VZB  = 1024;             // voxf zero blocks (64KB each)
static constexpr int CZB  = 16;               // counts zero blocks
static constexpr int WPB  = 128;              // feat waves per batch
static constexpr int PPW  = NPTS / WPB;       // 256 points per wave
static constexpr int CHUNK = 64;              // points per chunk
static constexpr int NCH  = PPW / CHUNK;      // 4 chunks per wave

// ws layout
static constexpr size_t OFF_COUNTS   = 0;                 // B*R3 ints = 1 MiB
static constexpr size_t OFF_PARTIALS = 1u << 20;          // SBT*3 floats

// ---------------- K1: slotted stats partials + zero voxf + zero counts ----------------
__global__ __launch_bounds__(256) void prep_kernel(const float* __restrict__ coords,
                                                   float* __restrict__ voxf,
                                                   int* __restrict__ counts,
                                                   float* __restrict__ partials) {
    int bx = blockIdx.x;
    int tid = threadIdx.x;
    if (bx < SBT) {
        int b = bx >> 6, sb = bx & 63;
        const float* cbase = coords + ((size_t)b * NPTS + sb * (NPTS / SB)) * 3;
        float sx = 0.f, sy = 0.f, sz = 0.f;
        #pragma unroll
        for (int k = 0; k < (NPTS / SB) / 256; ++k) {
            const float* p = cbase + (k * 256 + tid) * 3;
            float x = p[0], y = p[1], z = p[2];
            float m = (x + y + z) * (1.0f / 3.0f);
            float dx = x - m, dy = y - m, dz = z - m;
            sx += dx * dx; sy += dy * dy; sz += dz * dz;
        }
        #pragma unroll
        for (int off = 1; off < 64; off <<= 1) {
            sx += __shfl_xor(sx, off);
            sy += __shfl_xor(sy, off);
            sz += __shfl_xor(sz, off);
        }
        __shared__ float ls[3][4];
        int w = tid >> 6;
        if ((tid & 63) == 0) { ls[0][w] = sx; ls[1][w] = sy; ls[2][w] = sz; }
        __syncthreads();
        if (tid == 0) {
            float* o = partials + (size_t)bx * 3;
            o[0] = ls[0][0] + ls[0][1] + ls[0][2] + ls[0][3];
            o[1] = ls[1][0] + ls[1][1] + ls[1][2] + ls[1][3];
            o[2] = ls[2][0] + ls[2][1] + ls[2][2] + ls[2][3];
        }
        return;
    }
    int zb = bx - SBT;
    vfloat4 z = (vfloat4)(0.f);
    if (zb < VZB) {
        vfloat4* o4 = (vfloat4*)voxf + (size_t)zb * 4096;   // 64KB slice
        #pragma unroll
        for (int k = 0; k < 16; ++k) o4[k * 256 + tid] = z;
    } else {
        vfloat4* c4 = (vfloat4*)counts + (size_t)(zb - VZB) * 4096;
        #pragma unroll
        for (int k = 0; k < 16; ++k) c4[k * 256 + tid] = z;
    }
}

// ---------------- K2: fused points+feat, 256 points/wave, block-merged flush ----------------
// Per wave: 4 chunks of 64 points, double-buffered 16xfloat4 tile loads.
// lane=(sub,cslice). Run-length merge across chunks. FINAL flush is merged
// across the block's 4 waves via LDS when they agree on the voxel (common
// case) -> hot-address atomic chain depth 128 -> 32 per (batch,channel).
__global__ __launch_bounds__(256) void feat_kernel(const float* __restrict__ features,
                                                   const float* __restrict__ coords,
                                                   const float* __restrict__ partials,
                                                   float* __restrict__ nc_out,
                                                   int* __restrict__ counts,
                                                   float* __restrict__ voxf) {
    int b = blockIdx.y;
    int tid = threadIdx.x;
    int w = blockIdx.x * 4 + (tid >> 6);       // wave within batch 0..WPB-1
    int lane = tid & 63;
    int sub = lane >> 4;
    int cb  = (lane & 15) << 2;
    const float* fbase = features + (size_t)b * NPTS * CCH;
    const float* crd = coords + (size_t)b * NPTS * 3;
    int* cnt = counts + (size_t)b * R3;
    float* obase = voxf + (size_t)b * CCH * R3;
    int p0 = w * PPW;

    __shared__ int   sh_v[4];
    __shared__ int   sh_n[4];
    __shared__ float sh_val[4][64];

    // issue chunk-0 feature tile immediately
    float4 fbuf[2][16];
    #pragma unroll
    for (int i = 0; i < 16; ++i)
        fbuf[0][i] = *(const float4*)(fbase + (size_t)(p0 + i * 4 + sub) * CCH + cb);

    // per-wave denom re-reduce from slotted partials (lane = slot)
    const float* ps = partials + ((size_t)b * SB + lane) * 3;
    float qx = ps[0], qy = ps[1], qz = ps[2];
    #pragma unroll
    for (int off = 1; off < 64; off <<= 1) {
        qx += __shfl_xor(qx, off);
        qy += __shfl_xor(qy, off);
        qz += __shfl_xor(qz, off);
    }
    float mx = fmaxf(fmaxf(sqrtf(qx), sqrtf(qy)), sqrtf(qz));
    float rd = 0.5f / mx;                      // 1/denom, denom = 2*mx

    float4 acc = make_float4(0.f, 0.f, 0.f, 0.f);
    int curv = -1;
    int nrun = 0;

    auto flushRun = [&]() {
        if (curv < 0) return;
        if (lane == 0) atomicAdd(&cnt[curv], nrun);
        float sx = acc.x, sy = acc.y, sz = acc.z, sw = acc.w;
        sx += __shfl_xor(sx, 16); sx += __shfl_xor(sx, 32);
        sy += __shfl_xor(sy, 16); sy += __shfl_xor(sy, 32);
        sz += __shfl_xor(sz, 16); sz += __shfl_xor(sz, 32);
        sw += __shfl_xor(sw, 16); sw += __shfl_xor(sw, 32);
        float val = (sub == 0) ? sx : (sub == 1) ? sy : (sub == 2) ? sz : sw;
        atomicAdd(&obase[(size_t)(cb + sub) * R3 + curv], val);
    };

    #pragma unroll
    for (int c = 0; c < NCH; ++c) {
        int cur = c & 1;
        // prefetch next chunk's tile (in flight during this chunk's processing)
        if (c + 1 < NCH) {
            #pragma unroll
            for (int i = 0; i < 16; ++i)
                fbuf[cur ^ 1][i] = *(const float4*)(fbase +
                    (size_t)(p0 + (c + 1) * CHUNK + i * 4 + sub) * CCH + cb);
        }
        // this lane's own point for chunk c: nc + voxel id
        int pp = p0 + c * CHUNK + lane;
        float x = crd[pp * 3], y = crd[pp * 3 + 1], zz = crd[pp * 3 + 2];
        float m = (x + y + zz) * (1.0f / 3.0f);
        float fx = (x - m) * rd + 0.5f;
        float fy = (y - m) * rd + 0.5f;
        float fz = (zz - m) * rd + 0.5f;
        float tx = fminf(fmaxf(fx * (float)RR, 0.0f), (float)(RR - 1));
        float ty = fminf(fmaxf(fy * (float)RR, 0.0f), (float)(RR - 1));
        float tz = fminf(fmaxf(fz * (float)RR, 0.0f), (float)(RR - 1));
        float* onc = nc_out + (size_t)(b * NPTS + pp) * 3;
        onc[0] = tx; onc[1] = ty; onc[2] = tz;
        int v = (int)rintf(tx) * (RR * RR) + (int)rintf(ty) * RR + (int)rintf(tz);

        int v0 = __shfl(v, 0);
        if (__all(v == v0)) {
            if (v0 != curv) {
                flushRun();
                acc = make_float4(0.f, 0.f, 0.f, 0.f);
                nrun = 0;
                curv = v0;
            }
            #pragma unroll
            for (int i = 0; i < 16; ++i) {
                acc.x += fbuf[cur][i].x; acc.y += fbuf[cur][i].y;
                acc.z += fbuf[cur][i].z; acc.w += fbuf[cur][i].w;
            }
            nrun += CHUNK;
        } else {
            // rare: mixed voxels within chunk -> per-point atomics
            flushRun();
            acc = make_float4(0.f, 0.f, 0.f, 0.f);
            nrun = 0;
            curv = -1;
            atomicAdd(&cnt[v], 1);
            #pragma unroll
            for (int i = 0; i < 16; ++i) {
                int vv = __shfl(v, i * 4 + sub);
                size_t o = (size_t)cb * R3 + vv;
                atomicAdd(&obase[o],          fbuf[cur][i].x);
                atomicAdd(&obase[o + R3],     fbuf[cur][i].y);
                atomicAdd(&obase[o + 2 * R3], fbuf[cur][i].z);
                atomicAdd(&obase[o + 3 * R3], fbuf[cur][i].w);
            }
        }
    }

    // -------- block-merged final flush --------
    float val = 0.f;
    if (curv >= 0) {
        float sx = acc.x, sy = acc.y, sz = acc.z, sw = acc.w;
        sx += __shfl_xor(sx, 16); sx += __shfl_xor(sx, 32);
        sy += __shfl_xor(sy, 16); sy += __shfl_xor(sy, 32);
        sz += __shfl_xor(sz, 16); sz += __shfl_xor(sz, 32);
        sw += __shfl_xor(sw, 16); sw += __shfl_xor(sw, 32);
        val = (sub == 0) ? sx : (sub == 1) ? sy : (sub == 2) ? sz : sw;
    }
    int wv = tid >> 6;
    sh_v[wv] = curv;
    sh_n[wv] = nrun;
    sh_val[wv][lane] = val;
    __syncthreads();
    int vAll = sh_v[0];
    bool same = (vAll >= 0) && (sh_v[1] == vAll) && (sh_v[2] == vAll) && (sh_v[3] == vAll);
    if (same) {
        if (wv == 0) {
            float tot = sh_val[0][lane] + sh_val[1][lane] + sh_val[2][lane] + sh_val[3][lane];
            if (lane == 0) atomicAdd(&cnt[vAll], sh_n[0] + sh_n[1] + sh_n[2] + sh_n[3]);
            atomicAdd(&obase[(size_t)(cb + sub) * R3 + vAll], tot);
        }
    } else {
        // fallback: each wave flushes its own last run
        if (curv >= 0) {
            if (lane == 0) atomicAdd(&cnt[curv], nrun);
            atomicAdd(&obase[(size_t)(cb + sub) * R3 + curv], val);
        }
    }
}

// ---------------- K3: divide hot voxels by their counts ----------------
__global__ __launch_bounds__(256) void scale_kernel(const int* __restrict__ counts,
                                                    float* __restrict__ out) {
    int t = blockIdx.x * 256 + threadIdx.x;        // 0 .. B*R3-1
    int lane = threadIdx.x & 63;
    int b = t >> 15;                               // R3 = 32768
    int vox = t & (R3 - 1);
    int cnt = counts[t];
    unsigned long long mask = __ballot(cnt > 1);
    while (mask) {
        int src = __ffsll((long long)mask) - 1;
        mask &= mask - 1;
        int vv = __shfl(vox, src);
        int bb = __shfl(b, src);
        int cc = __shfl(cnt, src);
        float s = 1.0f / (float)cc;
        size_t o = ((size_t)bb * CCH + lane) * R3 + vv;
        out[o] *= s;
    }
}

extern "C" void kernel_launch(void* const* d_in, const int* in_sizes, int n_in,
                              void* d_out, int out_size, void* d_ws, size_t ws_size,
                              hipStream_t stream) {
    const float* features = (const float*)d_in[0];
    const float* coords   = (const float*)d_in[1];
    float* out = (float*)d_out;

    float* voxf = out;                                    // (B, C, R, R, R)
    float* nc   = out + (size_t)BATCH * CCH * R3;         // (B, N, 3)

    char* ws = (char*)d_ws;
    int*   counts   = (int*)(ws + OFF_COUNTS);
    float* partials = (float*)(ws + OFF_PARTIALS);

    prep_kernel<<<SBT + VZB + CZB, 256, 0, stream>>>(coords, voxf, counts, partials);

    dim3 fgrid(WPB / 4, BATCH);                           // 32 x 8 = 256 blocks
    feat_kernel<<<fgrid, 256, 0, stream>>>(features, coords, partials, nc, counts, voxf);

    scale_kernel<<<BATCH * R3 / 256, 256, 0, stream>>>(counts, voxf);
}

// Round 16
// 30.389 us; speedup vs baseline: 1.5788x; 1.0100x over previous
//
#include <hip/hip_runtime.h>
#include <math.h>

#define RR 32
#define R3 (RR*RR*RR)
#define BATCH 8
#define NPTS 32768
#define CCH 64

typedef float vfloat4 __attribute__((ext_vector_type(4)));

static constexpr int SB   = 64;               // stats slots per batch
static constexpr int SBT  = SB * BATCH;       // 512 stats blocks
static constexpr int VZB  = 1024;             // voxf zero blocks (64KB each)
static constexpr int CZB  = 16;               // counts zero blocks
static constexpr int WPB  = 256;              // feat waves per batch (2 blocks/CU)
static constexpr int PPW  = NPTS / WPB;       // 128 points per wave
static constexpr int CHUNK = 64;              // points per chunk
static constexpr int NCH  = PPW / CHUNK;      // 2 chunks per wave

// ws layout
static constexpr size_t OFF_COUNTS   = 0;                 // B*R3 ints = 1 MiB
static constexpr size_t OFF_PARTIALS = 1u << 20;          // SBT*3 floats

// ---------------- K1: slotted stats partials + zero voxf + zero counts ----------------
__global__ __launch_bounds__(256) void prep_kernel(const float* __restrict__ coords,
                                                   float* __restrict__ voxf,
                                                   int* __restrict__ counts,
                                                   float* __restrict__ partials) {
    int bx = blockIdx.x;
    int tid = threadIdx.x;
    if (bx < SBT) {
        int b = bx >> 6, sb = bx & 63;
        const float* cbase = coords + ((size_t)b * NPTS + sb * (NPTS / SB)) * 3;
        float sx = 0.f, sy = 0.f, sz = 0.f;
        #pragma unroll
        for (int k = 0; k < (NPTS / SB) / 256; ++k) {
            const float* p = cbase + (k * 256 + tid) * 3;
            float x = p[0], y = p[1], z = p[2];
            float m = (x + y + z) * (1.0f / 3.0f);
            float dx = x - m, dy = y - m, dz = z - m;
            sx += dx * dx; sy += dy * dy; sz += dz * dz;
        }
        #pragma unroll
        for (int off = 1; off < 64; off <<= 1) {
            sx += __shfl_xor(sx, off);
            sy += __shfl_xor(sy, off);
            sz += __shfl_xor(sz, off);
        }
        __shared__ float ls[3][4];
        int w = tid >> 6;
        if ((tid & 63) == 0) { ls[0][w] = sx; ls[1][w] = sy; ls[2][w] = sz; }
        __syncthreads();
        if (tid == 0) {
            float* o = partials + (size_t)bx * 3;
            o[0] = ls[0][0] + ls[0][1] + ls[0][2] + ls[0][3];
            o[1] = ls[1][0] + ls[1][1] + ls[1][2] + ls[1][3];
            o[2] = ls[2][0] + ls[2][1] + ls[2][2] + ls[2][3];
        }
        return;
    }
    int zb = bx - SBT;
    vfloat4 z = (vfloat4)(0.f);
    if (zb < VZB) {
        vfloat4* o4 = (vfloat4*)voxf + (size_t)zb * 4096;   // 64KB slice
        #pragma unroll
        for (int k = 0; k < 16; ++k) o4[k * 256 + tid] = z;
    } else {
        vfloat4* c4 = (vfloat4*)counts + (size_t)(zb - VZB) * 4096;
        #pragma unroll
        for (int k = 0; k < 16; ++k) c4[k * 256 + tid] = z;
    }
}

// ---------------- K2: fused points+feat, 128 points/wave, block-merged flush ----------------
// Per wave: 2 chunks of 64 points, double-buffered 16xfloat4 tile loads.
// lane=(sub,cslice). Run-length merge across chunks. FINAL flush is merged
// across the block's 4 waves via LDS when they agree on the voxel (common
// case) -> hot-address atomic chain depth 64 per (batch,channel).
__global__ __launch_bounds__(256) void feat_kernel(const float* __restrict__ features,
                                                   const float* __restrict__ coords,
                                                   const float* __restrict__ partials,
                                                   float* __restrict__ nc_out,
                                                   int* __restrict__ counts,
                                                   float* __restrict__ voxf) {
    int b = blockIdx.y;
    int tid = threadIdx.x;
    int w = blockIdx.x * 4 + (tid >> 6);       // wave within batch 0..WPB-1
    int lane = tid & 63;
    int sub = lane >> 4;
    int cb  = (lane & 15) << 2;
    const float* fbase = features + (size_t)b * NPTS * CCH;
    const float* crd = coords + (size_t)b * NPTS * 3;
    int* cnt = counts + (size_t)b * R3;
    float* obase = voxf + (size_t)b * CCH * R3;
    int p0 = w * PPW;

    __shared__ int   sh_v[4];
    __shared__ int   sh_n[4];
    __shared__ float sh_val[4][64];

    // issue chunk-0 feature tile immediately
    float4 fbuf[2][16];
    #pragma unroll
    for (int i = 0; i < 16; ++i)
        fbuf[0][i] = *(const float4*)(fbase + (size_t)(p0 + i * 4 + sub) * CCH + cb);

    // per-wave denom re-reduce from slotted partials (lane = slot)
    const float* ps = partials + ((size_t)b * SB + lane) * 3;
    float qx = ps[0], qy = ps[1], qz = ps[2];
    #pragma unroll
    for (int off = 1; off < 64; off <<= 1) {
        qx += __shfl_xor(qx, off);
        qy += __shfl_xor(qy, off);
        qz += __shfl_xor(qz, off);
    }
    float mx = fmaxf(fmaxf(sqrtf(qx), sqrtf(qy)), sqrtf(qz));
    float rd = 0.5f / mx;                      // 1/denom, denom = 2*mx

    float4 acc = make_float4(0.f, 0.f, 0.f, 0.f);
    int curv = -1;
    int nrun = 0;

    auto flushRun = [&]() {
        if (curv < 0) return;
        if (lane == 0) atomicAdd(&cnt[curv], nrun);
        float sx = acc.x, sy = acc.y, sz = acc.z, sw = acc.w;
        sx += __shfl_xor(sx, 16); sx += __shfl_xor(sx, 32);
        sy += __shfl_xor(sy, 16); sy += __shfl_xor(sy, 32);
        sz += __shfl_xor(sz, 16); sz += __shfl_xor(sz, 32);
        sw += __shfl_xor(sw, 16); sw += __shfl_xor(sw, 32);
        float val = (sub == 0) ? sx : (sub == 1) ? sy : (sub == 2) ? sz : sw;
        atomicAdd(&obase[(size_t)(cb + sub) * R3 + curv], val);
    };

    #pragma unroll
    for (int c = 0; c < NCH; ++c) {
        int cur = c & 1;
        // prefetch next chunk's tile (in flight during this chunk's processing)
        if (c + 1 < NCH) {
            #pragma unroll
            for (int i = 0; i < 16; ++i)
                fbuf[cur ^ 1][i] = *(const float4*)(fbase +
                    (size_t)(p0 + (c + 1) * CHUNK + i * 4 + sub) * CCH + cb);
        }
        // this lane's own point for chunk c: nc + voxel id
        int pp = p0 + c * CHUNK + lane;
        float x = crd[pp * 3], y = crd[pp * 3 + 1], zz = crd[pp * 3 + 2];
        float m = (x + y + zz) * (1.0f / 3.0f);
        float fx = (x - m) * rd + 0.5f;
        float fy = (y - m) * rd + 0.5f;
        float fz = (zz - m) * rd + 0.5f;
        float tx = fminf(fmaxf(fx * (float)RR, 0.0f), (float)(RR - 1));
        float ty = fminf(fmaxf(fy * (float)RR, 0.0f), (float)(RR - 1));
        float tz = fminf(fmaxf(fz * (float)RR, 0.0f), (float)(RR - 1));
        float* onc = nc_out + (size_t)(b * NPTS + pp) * 3;
        onc[0] = tx; onc[1] = ty; onc[2] = tz;
        int v = (int)rintf(tx) * (RR * RR) + (int)rintf(ty) * RR + (int)rintf(tz);

        int v0 = __shfl(v, 0);
        if (__all(v == v0)) {
            if (v0 != curv) {
                flushRun();
                acc = make_float4(0.f, 0.f, 0.f, 0.f);
                nrun = 0;
                curv = v0;
            }
            #pragma unroll
            for (int i = 0; i < 16; ++i) {
                acc.x += fbuf[cur][i].x; acc.y += fbuf[cur][i].y;
                acc.z += fbuf[cur][i].z; acc.w += fbuf[cur][i].w;
            }
            nrun += CHUNK;
        } else {
            // rare: mixed voxels within chunk -> per-point atomics
            flushRun();
            acc = make_float4(0.f, 0.f, 0.f, 0.f);
            nrun = 0;
            curv = -1;
            atomicAdd(&cnt[v], 1);
            #pragma unroll
            for (int i = 0; i < 16; ++i) {
                int vv = __shfl(v, i * 4 + sub);
                size_t o = (size_t)cb * R3 + vv;
                atomicAdd(&obase[o],          fbuf[cur][i].x);
                atomicAdd(&obase[o + R3],     fbuf[cur][i].y);
                atomicAdd(&obase[o + 2 * R3], fbuf[cur][i].z);
                atomicAdd(&obase[o + 3 * R3], fbuf[cur][i].w);
            }
        }
    }

    // -------- block-merged final flush --------
    float val = 0.f;
    if (curv >= 0) {
        float sx = acc.x, sy = acc.y, sz = acc.z, sw = acc.w;
        sx += __shfl_xor(sx, 16); sx += __shfl_xor(sx, 32);
        sy += __shfl_xor(sy, 16); sy += __shfl_xor(sy, 32);
        sz += __shfl_xor(sz, 16); sz += __shfl_xor(sz, 32);
        sw += __shfl_xor(sw, 16); sw += __shfl_xor(sw, 32);
        val = (sub == 0) ? sx : (sub == 1) ? sy : (sub == 2) ? sz : sw;
    }
    int wv = tid >> 6;
    sh_v[wv] = curv;
    sh_n[wv] = nrun;
    sh_val[wv][lane] = val;
    __syncthreads();
    int vAll = sh_v[0];
    bool same = (vAll >= 0) && (sh_v[1] == vAll) && (sh_v[2] == vAll) && (sh_v[3] == vAll);
    if (same) {
        if (wv == 0) {
            float tot = sh_val[0][lane] + sh_val[1][lane] + sh_val[2][lane] + sh_val[3][lane];
            if (lane == 0) atomicAdd(&cnt[vAll], sh_n[0] + sh_n[1] + sh_n[2] + sh_n[3]);
            atomicAdd(&obase[(size_t)(cb + sub) * R3 + vAll], tot);
        }
    } else {
        // fallback: each wave flushes its own last run
        if (curv >= 0) {
            if (lane == 0) atomicAdd(&cnt[curv], nrun);
            atomicAdd(&obase[(size_t)(cb + sub) * R3 + curv], val);
        }
    }
}

// ---------------- K3: divide hot voxels by their counts ----------------
__global__ __launch_bounds__(256) void scale_kernel(const int* __restrict__ counts,
                                                    float* __restrict__ out) {
    int t = blockIdx.x * 256 + threadIdx.x;        // 0 .. B*R3-1
    int lane = threadIdx.x & 63;
    int b = t >> 15;                               // R3 = 32768
    int vox = t & (R3 - 1);
    int cnt = counts[t];
    unsigned long long mask = __ballot(cnt > 1);
    while (mask) {
        int src = __ffsll((long long)mask) - 1;
        mask &= mask - 1;
        int vv = __shfl(vox, src);
        int bb = __shfl(b, src);
        int cc = __shfl(cnt, src);
        float s = 1.0f / (float)cc;
        size_t o = ((size_t)bb * CCH + lane) * R3 + vv;
        out[o] *= s;
    }
}

extern "C" void kernel_launch(void* const* d_in, const int* in_sizes, int n_in,
                              void* d_out, int out_size, void* d_ws, size_t ws_size,
                              hipStream_t stream) {
    const float* features = (const float*)d_in[0];
    const float* coords   = (const float*)d_in[1];
    float* out = (float*)d_out;

    float* voxf = out;                                    // (B, C, R, R, R)
    float* nc   = out + (size_t)BATCH * CCH * R3;         // (B, N, 3)

    char* ws = (char*)d_ws;
    int*   counts   = (int*)(ws + OFF_COUNTS);
    float* partials = (float*)(ws + OFF_PARTIALS);

    prep_kernel<<<SBT + VZB + CZB, 256, 0, stream>>>(coords, voxf, counts, partials);

    dim3 fgrid(WPB / 4, BATCH);                           // 64 x 8 = 512 blocks
    feat_kernel<<<fgrid, 256, 0, stream>>>(features, coords, partials, nc, counts, voxf);

    scale_kernel<<<BATCH * R3 / 256, 256, 0, stream>>>(counts, voxf);
}